// Round 8
// baseline (399.258 us; speedup 1.0000x reference)
//
#include <hip/hip_runtime.h>
#include <hip/hip_bf16.h>

#define N_NODES 10000
#define N_EDGES 30000
#define F_NODE  32
#define F_EDGE  8
#define EMB     64
#define HID     16
#define NGRAPH  64

__device__ __forceinline__ unsigned short f2bf(float f) {
    __hip_bfloat16 h = __float2bfloat16(f);
    return *(unsigned short*)&h;
}

// ---- precompute core: block handles 8 nodes, all 16 h. Wave w owns h in [4w,4w+4).
//   U[n][o][h] = sum_i x[n,i]*w2[h,i*EMB+o]  (bf16, stored as packed 8B per (j,o))
//   XB[n,o]   = sum_i x[n,i]*b2[i*EMB+o]
//   x reads are wave-uniform -> scalar loads (xg must NOT have been scalar-read-stale; see call sites)
template <int IN>
__device__ __forceinline__ void pre_core(int n0, int t,
        const float* xg, const float* __restrict__ w2, const float* __restrict__ bb2,
        __hip_bfloat16* __restrict__ U, float* __restrict__ XB) {
    int h1 = t >> 6;            // wave id 0..3
    int o  = t & 63;
    float acc[4][8];
#pragma unroll
    for (int k = 0; k < 4; k++)
#pragma unroll
        for (int j = 0; j < 8; j++) acc[k][j] = 0.f;
#pragma unroll
    for (int k = 0; k < 4; k++) {
        int h = h1 * 4 + k;
        const float* wrow = w2 + (size_t)h * (IN * EMB) + o;
        for (int i = 0; i < IN; i += 4) {
            float w0 = wrow[(i + 0) * EMB];
            float w1 = wrow[(i + 1) * EMB];
            float w2v = wrow[(i + 2) * EMB];
            float w3 = wrow[(i + 3) * EMB];
#pragma unroll
            for (int j = 0; j < 8; j++) {
                const float* xj = xg + (size_t)(n0 + j) * IN + i;   // uniform -> s_load
                float a = acc[k][j];
                a = fmaf(xj[0], w0, a);
                a = fmaf(xj[1], w1, a);
                a = fmaf(xj[2], w2v, a);
                a = fmaf(xj[3], w3, a);
                acc[k][j] = a;
            }
        }
    }
#pragma unroll
    for (int j = 0; j < 8; j++) {
        unsigned lo = (unsigned)f2bf(acc[0][j]) | ((unsigned)f2bf(acc[1][j]) << 16);
        unsigned hi = (unsigned)f2bf(acc[2][j]) | ((unsigned)f2bf(acc[3][j]) << 16);
        uint2 v; v.x = lo; v.y = hi;
        *(uint2*)(U + (size_t)(n0 + j) * (EMB * HID) + o * HID + h1 * 4) = v;
    }
    // XB: 8 nodes x 64 cols, 2 nodes per wave
#pragma unroll
    for (int r = 0; r < 2; r++) {
        int j = h1 + r * 4;
        float s = 0.f;
        for (int i = 0; i < IN; i++) s += xg[(size_t)(n0 + j) * IN + i] * bb2[i * EMB + o];
        XB[(n0 + j) * EMB + o] = s;
    }
}

// ---- update core: block handles 8 nodes; X=relu(AGG + x@root + bias); optional AGG re-zero / pool
//   xg (old x) is read via VECTOR loads into LDS (keeps the scalar cache untouched for X).
template <int IN, bool POOLING, bool ZAGG>
__device__ __forceinline__ void upd_core(int n0, int t,
        const float* xg, const float* __restrict__ root, const float* __restrict__ bias,
        float* AGG, float* X, const int* __restrict__ batch, unsigned* __restrict__ POOL) {
    __shared__ float xold[8][IN];
    for (int v = t; v < 8 * IN; v += 256) xold[v / IN][v % IN] = xg[(size_t)n0 * IN + v];
    __syncthreads();
#pragma unroll
    for (int r = 0; r < 2; r++) {
        int v = t + r * 256;
        int j = v >> 6, o = v & 63;
        int n = n0 + j;
        float s = AGG[n * EMB + o] + bias[o];
#pragma unroll
        for (int i = 0; i < IN; i++) s = fmaf(xold[j][i], root[i * EMB + o], s);
        s = fmaxf(s, 0.f);
        X[n * EMB + o] = s;
        if (ZAGG) AGG[n * EMB + o] = 0.f;
        if (POOLING) atomicMax(&POOL[batch[n] * EMB + o], __float_as_uint(s));
    }
}

// ---- kernel 1: pre conv0 (blocks 0..1249) + edge MLP hidden (1250..1367) + POOL zero (1368..1383)
__global__ void __launch_bounds__(256) k_pre0(const float* __restrict__ x_p,
        const float* __restrict__ ea,
        const float* __restrict__ nn0_w1, const float* __restrict__ nn0_b1,
        const float* __restrict__ nn0_w2, const float* __restrict__ nn0_b2,
        const float* __restrict__ nn1_w1, const float* __restrict__ nn1_b1,
        float* __restrict__ A0, float* __restrict__ A1,
        __hip_bfloat16* __restrict__ U, float* __restrict__ XB,
        float* __restrict__ AGG, unsigned* __restrict__ POOL) {
    int b = blockIdx.x, t = threadIdx.x;
    if (b < N_NODES / 8) {
        int n0 = b * 8;
#pragma unroll
        for (int r = 0; r < 2; r++) AGG[n0 * EMB + t + r * 256] = 0.f;
        pre_core<F_NODE>(n0, t, x_p, nn0_w2, nn0_b2, U, XB);
    } else if (b < N_NODES / 8 + (N_EDGES + 255) / 256) {
        int e = (b - N_NODES / 8) * 256 + t;
        if (e >= N_EDGES) return;
        float f[F_EDGE];
#pragma unroll
        for (int i = 0; i < F_EDGE; i++) f[i] = ea[e * F_EDGE + i];
#pragma unroll
        for (int h = 0; h < HID; h++) {
            float s0 = nn0_b1[h];
            float s1 = nn1_b1[h];
#pragma unroll
            for (int i = 0; i < F_EDGE; i++) {
                s0 += f[i] * nn0_w1[i * HID + h];
                s1 += f[i] * nn1_w1[i * HID + h];
            }
            A0[e * HID + h] = fmaxf(s0, 0.f);
            A1[e * HID + h] = fmaxf(s1, 0.f);
        }
    } else {
        POOL[(b - N_NODES / 8 - (N_EDGES + 255) / 256) * 256 + t] = 0u;
    }
}

// ---- gather: 4 edges/block; msg = XB[src] + sum_h A[e,h]*U[src][o][h]; atomicAdd AGG[dst]
__global__ void __launch_bounds__(256) k_gather(const float* __restrict__ A,
        const __hip_bfloat16* __restrict__ U, const float* __restrict__ XB,
        const int* __restrict__ src, const int* __restrict__ dst,
        float* __restrict__ AGG) {
    __shared__ float As[4][HID];
    int t = threadIdx.x;
    if (t < 4 * HID) As[t >> 4][t & 15] = A[(size_t)blockIdx.x * 4 * HID + t];
    __syncthreads();
    int eb = t >> 6, o = t & 63;
    int e = blockIdx.x * 4 + eb;          // 30000/4 = 7500 exact
    int s = src[e], d = dst[e];
    float m = XB[s * EMB + o];
    const uint4* Up = (const uint4*)(U + (size_t)s * (EMB * HID) + o * HID);
    uint4 u0 = Up[0];
    uint4 u1 = Up[1];
    const float* Ae = As[eb];
    float f;
    f = __uint_as_float(u0.x << 16);         m = fmaf(Ae[0],  f, m);
    f = __uint_as_float(u0.x & 0xffff0000u); m = fmaf(Ae[1],  f, m);
    f = __uint_as_float(u0.y << 16);         m = fmaf(Ae[2],  f, m);
    f = __uint_as_float(u0.y & 0xffff0000u); m = fmaf(Ae[3],  f, m);
    f = __uint_as_float(u0.z << 16);         m = fmaf(Ae[4],  f, m);
    f = __uint_as_float(u0.z & 0xffff0000u); m = fmaf(Ae[5],  f, m);
    f = __uint_as_float(u0.w << 16);         m = fmaf(Ae[6],  f, m);
    f = __uint_as_float(u0.w & 0xffff0000u); m = fmaf(Ae[7],  f, m);
    f = __uint_as_float(u1.x << 16);         m = fmaf(Ae[8],  f, m);
    f = __uint_as_float(u1.x & 0xffff0000u); m = fmaf(Ae[9],  f, m);
    f = __uint_as_float(u1.y << 16);         m = fmaf(Ae[10], f, m);
    f = __uint_as_float(u1.y & 0xffff0000u); m = fmaf(Ae[11], f, m);
    f = __uint_as_float(u1.z << 16);         m = fmaf(Ae[12], f, m);
    f = __uint_as_float(u1.z & 0xffff0000u); m = fmaf(Ae[13], f, m);
    f = __uint_as_float(u1.w << 16);         m = fmaf(Ae[14], f, m);
    f = __uint_as_float(u1.w & 0xffff0000u); m = fmaf(Ae[15], f, m);
    atomicAdd(&AGG[d * EMB + o], m);
}

// ---- fused: update conv(k) for 8 nodes, then precompute conv(k+1) for the SAME 8 nodes.
//   No grid barrier needed: pre[n] depends only on X[n] written by this block.
//   X round-trip: upd reads old x via vector loads (LDS); pre re-reads new X via scalar
//   loads — first scalar touch of X this kernel, so the scalar cache cannot be stale.
template <int INU>
__global__ void __launch_bounds__(256) k_upd_pre(const float* xg_old,
        const float* __restrict__ root, const float* __restrict__ bias,
        const float* __restrict__ w2, const float* __restrict__ bb2,
        float* AGG, float* X, __hip_bfloat16* __restrict__ U, float* __restrict__ XB) {
    int n0 = blockIdx.x * 8, t = threadIdx.x;
    upd_core<INU, false, true>(n0, t, xg_old, root, bias, AGG, X, nullptr, nullptr);
    __syncthreads();
    pre_core<EMB>(n0, t, X, w2, bb2, U, XB);
}

// ---- final update + max-pool (post-ReLU >= 0: uint atomicMax is order-preserving)
__global__ void __launch_bounds__(256) k_upd_pool(const float* xg_old,
        const float* __restrict__ root, const float* __restrict__ bias,
        float* AGG, float* X, const int* __restrict__ batch, unsigned* __restrict__ POOL) {
    int n0 = blockIdx.x * 8, t = threadIdx.x;
    upd_core<EMB, true, false>(n0, t, xg_old, root, bias, AGG, X, batch, POOL);
}

// ---- head: out[g] = (pooled[g]@lin0_w + lin0_b) @ lin1_w + lin1_b
__global__ void __launch_bounds__(256) k_head(const unsigned* __restrict__ POOL,
        const float* __restrict__ l0w, const float* __restrict__ l0b,
        const float* __restrict__ l1w, const float* __restrict__ l1b,
        float* __restrict__ out) {
    __shared__ float P[NGRAPH * EMB];
    int t = threadIdx.x;  // 256
    for (int idx = t; idx < NGRAPH * EMB; idx += 256) P[idx] = __uint_as_float(POOL[idx]);
    __syncthreads();
    if (t < NGRAPH) {
        int g = t;
        float acc = l1b[0];
        for (int o2 = 0; o2 < EMB; o2++) {
            float h = l0b[o2];
            for (int o = 0; o < EMB; o++) h += P[g * EMB + o] * l0w[o * EMB + o2];
            acc += h * l1w[o2];
        }
        out[g] = acc;
    }
}

extern "C" void kernel_launch(void* const* d_in, const int* in_sizes, int n_in,
                              void* d_out, int out_size, void* d_ws, size_t ws_size,
                              hipStream_t stream) {
    const float* x_p    = (const float*)d_in[0];
    const float* ea     = (const float*)d_in[2];
    const int*   eidx   = (const int*)d_in[4];
    const int*   batch  = (const int*)d_in[5];
    const float* nn0_w1 = (const float*)d_in[6];
    const float* nn0_b1 = (const float*)d_in[7];
    const float* nn0_w2 = (const float*)d_in[8];
    const float* nn0_b2 = (const float*)d_in[9];
    const float* nn1_w1 = (const float*)d_in[10];
    const float* nn1_b1 = (const float*)d_in[11];
    const float* nn1_w2 = (const float*)d_in[12];
    const float* nn1_b2 = (const float*)d_in[13];
    const float* root0  = (const float*)d_in[14];
    const float* bias0  = (const float*)d_in[15];
    const float* root1  = (const float*)d_in[16];
    const float* bias1  = (const float*)d_in[17];
    const float* root2  = (const float*)d_in[18];
    const float* bias2  = (const float*)d_in[19];
    const float* lin0_w = (const float*)d_in[20];
    const float* lin0_b = (const float*)d_in[21];
    const float* lin1_w = (const float*)d_in[22];
    const float* lin1_b = (const float*)d_in[23];

    const int* src = eidx;
    const int* dst = eidx + N_EDGES;

    char* ws = (char*)d_ws;
    float* A0   = (float*)ws;                 ws += (size_t)N_EDGES * HID * 4;
    float* A1   = (float*)ws;                 ws += (size_t)N_EDGES * HID * 4;
    __hip_bfloat16* U = (__hip_bfloat16*)ws;  ws += (size_t)N_NODES * HID * EMB * 2;  // [n][o][h]
    float* XB   = (float*)ws;                 ws += (size_t)N_NODES * EMB * 4;
    float* X    = (float*)ws;                 ws += (size_t)N_NODES * EMB * 4;
    float* AGG  = (float*)ws;                 ws += (size_t)N_NODES * EMB * 4;
    unsigned* POOL = (unsigned*)ws;           ws += (size_t)NGRAPH * EMB * 4;

    const int PRE0_GRID = N_NODES / 8 + (N_EDGES + 255) / 256 + (NGRAPH * EMB) / 256; // 1384
    const int NODE_GRID = N_NODES / 8;        // 1250
    const int GAT_GRID  = N_EDGES / 4;        // 7500

    // 1: pre conv0 + edge MLPs + AGG/POOL zeroing
    k_pre0<<<PRE0_GRID, 256, 0, stream>>>(x_p, ea, nn0_w1, nn0_b1, nn0_w2, nn0_b2,
                                          nn1_w1, nn1_b1, A0, A1, U, XB, AGG, POOL);
    // 2: gather conv0
    k_gather<<<GAT_GRID, 256, 0, stream>>>(A0, U, XB, src, dst, AGG);
    // 3: update conv0 + pre conv1
    k_upd_pre<F_NODE><<<NODE_GRID, 256, 0, stream>>>(x_p, root0, bias0, nn1_w2, nn1_b2, AGG, X, U, XB);
    // 4: gather conv1
    k_gather<<<GAT_GRID, 256, 0, stream>>>(A1, U, XB, src, dst, AGG);
    // 5: update conv1 + pre conv2
    k_upd_pre<EMB><<<NODE_GRID, 256, 0, stream>>>(X, root1, bias1, nn1_w2, nn1_b2, AGG, X, U, XB);
    // 6: gather conv2
    k_gather<<<GAT_GRID, 256, 0, stream>>>(A1, U, XB, src, dst, AGG);
    // 7: update conv2 + max-pool
    k_upd_pool<<<NODE_GRID, 256, 0, stream>>>(X, root2, bias2, AGG, X, batch, POOL);
    // 8: head
    k_head<<<1, 256, 0, stream>>>(POOL, lin0_w, lin0_b, lin1_w, lin1_b, (float*)d_out);
}